// Round 10
// baseline (146.005 us; speedup 1.0000x reference)
//
#include <hip/hip_runtime.h>
#include <hip/hip_bf16.h>

#define NN 6144
#define NF 512
#define NH 256
#define BR 32                  // K3 rows per block
#define NTT (NN / 64)          // 96 j-tiles total
#define NW (NN / 64)           // 96 mask words per row (24 groups x 4)
#define NG 24                  // mask groups (256 cols each)
#define HSTRIDE 132            // padded LDS row stride (f32)
#define MASKBLK 3072           // kprep: mask blocks (2 rows each)

typedef __attribute__((ext_vector_type(4))) float f32x4;
typedef __attribute__((ext_vector_type(2))) float f32x2;
typedef __attribute__((ext_vector_type(8))) short s16x8;
typedef __attribute__((ext_vector_type(4))) short s16x4;
typedef __attribute__((ext_vector_type(4))) int i32x4;
typedef __attribute__((ext_vector_type(2))) unsigned long long u64x2;

__device__ __forceinline__ ushort f2bf(float f) {
    unsigned u = __builtin_bit_cast(unsigned, f);
    u += 0x7fffu + ((u >> 16) & 1u);   // RNE (finite values only)
    return (ushort)(u >> 16);
}

__device__ __forceinline__ float wave_red_add(float v) {
#pragma unroll
    for (int s = 32; s; s >>= 1) v += __shfl_xor(v, s);
    return v;
}

// ---------------- Kprep: fused {adj -> interleaved u64 bitmask} + {W -> WbT}
// blocks 0..3071: mask, 2 rows/block, 2 waves/row (half-row each, 12 groups).
// Interleaved format: word q of group g holds cols g*256 + 4*lane + q.
// blocks 3072..3583: W (512x256 f32, k-major) -> WbT (256x512 bf16, n-major).
__global__ __launch_bounds__(256) void kprep(const int* __restrict__ adj,
                                             unsigned long long* __restrict__ maskb,
                                             const float* __restrict__ W,
                                             ushort* __restrict__ WbT) {
    const int bid = blockIdx.x;
    const int t = threadIdx.x;
    if (bid >= MASKBLK) {
        int idx = (bid - MASKBLK) * 256 + t;   // 0..131071
        int k = idx >> 8, n = idx & 255;
        WbT[n * NF + k] = f2bf(W[idx]);
        return;
    }
    const int lane = t & 63, wid = t >> 6;
    const int row = bid * 2 + (wid >> 1);
    const int half = wid & 1;                  // which 12-group half of the row
    const i32x4* ap = reinterpret_cast<const i32x4*>(adj + (size_t)row * NN)
                      + half * (12 * 64) + lane;
    unsigned long long* mrow = maskb + (size_t)row * NW + half * 48;
#pragma unroll
    for (int g = 0; g < 12; ++g) {
        i32x4 v = __builtin_nontemporal_load(ap + g * 64);   // 1KB/wave, read-once
        unsigned long long w0 = __ballot(v[0] != 0);
        unsigned long long w1 = __ballot(v[1] != 0);
        unsigned long long w2 = __ballot(v[2] != 0);
        unsigned long long w3 = __ballot(v[3] != 0);
        if (lane == 0) {
            u64x2 a = {w0, w1}, b = {w2, w3};
            *reinterpret_cast<u64x2*>(mrow + g * 4) = a;
            *reinterpret_cast<u64x2*>(mrow + g * 4 + 2) = b;
        }
    }
}

// ---------------- K1: Wh = x @ W  (6144x512 * 512x256), MFMA bf16
// outputs: Wh f32 [6144][256]; B2 bf16 blocked [j/8][col][j%8]
__global__ __launch_bounds__(256) void k1_gemm(const float* __restrict__ x,
                                               const ushort* __restrict__ WbT,
                                               float* __restrict__ Wh,
                                               ushort* __restrict__ B2) {
    __shared__ ushort Asm[128 * 64];   // [row][k] swizzled
    __shared__ ushort Bsm[64 * 64];    // [n][k] swizzled
    const int t = threadIdx.x, lane = t & 63, wid = t >> 6;
    const int rb = blockIdx.x;   // 0..47 (128 rows)
    const int cb = blockIdx.y;   // 0..3  (64 cols)
    const int wrow = wid >> 1, wcol = wid & 1;
    f32x4 acc[4][2];
#pragma unroll
    for (int i = 0; i < 4; ++i)
#pragma unroll
        for (int j = 0; j < 2; ++j) acc[i][j] = (f32x4){0.f, 0.f, 0.f, 0.f};

    for (int kt = 0; kt < NF; kt += 64) {
        __syncthreads();
#pragma unroll
        for (int c = 0; c < 4; ++c) {
            int idx = c * 256 + t;           // 0..1023
            int row = idx >> 3, k8 = idx & 7;
            const float* src = x + (rb * 128 + row) * NF + kt + k8 * 8;
            float4 lo = *reinterpret_cast<const float4*>(src);
            float4 hi = *reinterpret_cast<const float4*>(src + 4);
            union { s16x8 v; ushort u[8]; } pk;
            pk.u[0] = f2bf(lo.x); pk.u[1] = f2bf(lo.y);
            pk.u[2] = f2bf(lo.z); pk.u[3] = f2bf(lo.w);
            pk.u[4] = f2bf(hi.x); pk.u[5] = f2bf(hi.y);
            pk.u[6] = f2bf(hi.z); pk.u[7] = f2bf(hi.w);
            int byte = (row * 128 + k8 * 16) ^ ((row & 7) << 4);
            *reinterpret_cast<s16x8*>((char*)Asm + byte) = pk.v;
        }
#pragma unroll
        for (int c = 0; c < 2; ++c) {
            int idx = c * 256 + t;           // 0..511
            int row = idx >> 3, k8 = idx & 7;
            s16x8 v = *reinterpret_cast<const s16x8*>(WbT + (cb * 64 + row) * NF + kt + k8 * 8);
            int byte = (row * 128 + k8 * 16) ^ ((row & 7) << 4);
            *reinterpret_cast<s16x8*>((char*)Bsm + byte) = v;
        }
        __syncthreads();
#pragma unroll
        for (int kk = 0; kk < 64; kk += 32) {
            const int kbyte = (kk + ((lane >> 4) * 8)) * 2;
            s16x8 af[4], bfr[2];
#pragma unroll
            for (int fi = 0; fi < 4; ++fi) {
                int row = wrow * 64 + fi * 16 + (lane & 15);
                int byte = (row * 128 + kbyte) ^ ((row & 7) << 4);
                af[fi] = *reinterpret_cast<const s16x8*>((char*)Asm + byte);
            }
#pragma unroll
            for (int fj = 0; fj < 2; ++fj) {
                int nn = wcol * 32 + fj * 16 + (lane & 15);
                int byte = (nn * 128 + kbyte) ^ ((nn & 7) << 4);
                bfr[fj] = *reinterpret_cast<const s16x8*>((char*)Bsm + byte);
            }
#pragma unroll
            for (int fi = 0; fi < 4; ++fi)
#pragma unroll
                for (int fj = 0; fj < 2; ++fj)
                    acc[fi][fj] = __builtin_amdgcn_mfma_f32_16x16x32_bf16(
                        af[fi], bfr[fj], acc[fi][fj], 0, 0, 0);
        }
    }
#pragma unroll
    for (int fi = 0; fi < 4; ++fi)
#pragma unroll
        for (int fj = 0; fj < 2; ++fj) {
            int grow0 = rb * 128 + wrow * 64 + fi * 16 + (lane >> 4) * 4;  // j; %8 in {0,4}
            int gcol = cb * 64 + wcol * 32 + fj * 16 + (lane & 15);
            union { s16x4 v; ushort u[4]; } pk;
#pragma unroll
            for (int r = 0; r < 4; ++r) {
                float v = acc[fi][fj][r];
                Wh[(grow0 + r) * NH + gcol] = v;
                pk.u[r] = f2bf(v);
            }
            *reinterpret_cast<s16x4*>(B2 + (grow0 >> 3) * 2048 + gcol * 8 + (grow0 & 7)) = pk.v;
        }
}

// ---------------- K2: f1 = Wh@a1, f2 = Wh@a2 (one wave per row)
__global__ __launch_bounds__(256) void k2_f12(const float* __restrict__ Wh,
                                              const float* __restrict__ a,
                                              float* __restrict__ f1,
                                              float* __restrict__ f2) {
    int row = blockIdx.x * 4 + (threadIdx.x >> 6);
    int lane = threadIdx.x & 63;
    float4 wv = *reinterpret_cast<const float4*>(Wh + row * NH + lane * 4);
    float4 a1 = *reinterpret_cast<const float4*>(a + lane * 4);
    float4 a2 = *reinterpret_cast<const float4*>(a + NH + lane * 4);
    float d1 = wv.x * a1.x + wv.y * a1.y + wv.z * a1.z + wv.w * a1.w;
    float d2 = wv.x * a2.x + wv.y * a2.y + wv.z * a2.z + wv.w * a2.w;
    d1 = wave_red_add(d1);
    d2 = wave_red_add(d2);
    if (lane == 0) { f1[row] = d1; f2[row] = d2; }
}

// ---------------- K3: fully-fused attention — FINAL rows, no partial outputs
// Block: 32 rows x 128 cols (grid 192 x 2). 4 waves; wave wid sweeps tiles
// jt = wid + it*4 (jt&3 == wid), consuming the interleaved mask format:
// bit for col C+q = (word[q&3] >> (wid*16 + l4*2 + kk*8 + (q>>2))) & 1.
__global__ __launch_bounds__(256) void k3_attn(const unsigned long long* __restrict__ maskb,
                                               const ushort* __restrict__ B2,
                                               const float* __restrict__ f1,
                                               const float* __restrict__ f2,
                                               const float* __restrict__ fcW,
                                               float* __restrict__ out1h,
                                               float* __restrict__ ph) {
    __shared__ float Hlds[2][BR * HSTRIDE];   // 2 x 16.9 KB
    __shared__ float Zlds[2][BR];
    const int t = threadIdx.x, lane = t & 63, wid = t >> 6;
    const int rb = blockIdx.x;        // 0..191 (32 rows each)
    const int cb = blockIdx.y;        // 0..1   (128 cols each)
    const int row0 = rb * BR;
    const int col0 = cb * 128;
    const int r15 = lane & 15, l4 = lane >> 4;
    const int sh = l4 * 8;
    const int base = wid * 16 + l4 * 2;   // bit base within mask words

    const float f1v0 = f1[row0 + r15];
    const float f1v1 = f1[row0 + 16 + r15];
    const unsigned long long* mp0 = maskb + (size_t)(row0 + r15) * NW;
    const unsigned long long* mp1 = mp0 + 16 * NW;
    const float* f2p = f2 + sh;
    const ushort* bb = B2 + (size_t)l4 * 2048 + (col0 + r15) * 8;

    f32x4 acc[2][8];
#pragma unroll
    for (int i = 0; i < 2; ++i)
#pragma unroll
        for (int j = 0; j < 8; ++j) acc[i][j] = (f32x4){0.f, 0.f, 0.f, 0.f};
    float zs0 = 0.f, zs1 = 0.f;

#pragma unroll 2
    for (int it = 0; it < NG; ++it) {
        const int jt = wid + it * 4;
        // group mask words (interleaved format), both row-halves
        u64x2 wAa = *reinterpret_cast<const u64x2*>(mp0 + it * 4);
        u64x2 wAb = *reinterpret_cast<const u64x2*>(mp0 + it * 4 + 2);
        u64x2 wBa = *reinterpret_cast<const u64x2*>(mp1 + it * 4);
        u64x2 wBb = *reinterpret_cast<const u64x2*>(mp1 + it * 4 + 2);
        unsigned long long wv[2][4] = {{wAa[0], wAa[1], wAb[0], wAb[1]},
                                       {wBa[0], wBa[1], wBb[0], wBb[1]}};
        f32x4 g[2][2];
#pragma unroll
        for (int kk = 0; kk < 2; ++kk)
#pragma unroll
            for (int h = 0; h < 2; ++h)
                g[kk][h] = *reinterpret_cast<const f32x4*>(f2p + jt * 64 + kk * 32 + h * 4);
        // --- wgen: build A-fragments in registers from interleaved mask bits
        s16x8 af[2][2];
#pragma unroll
        for (int fi = 0; fi < 2; ++fi) {
            const float f1v = fi ? f1v1 : f1v0;
#pragma unroll
            for (int kk = 0; kk < 2; ++kk) {
                union { s16x8 v; ushort u[8]; } pk;
                float zl = 0.f;
#pragma unroll
                for (int q = 0; q < 8; ++q) {
                    float e = f1v + g[kk][q >> 2][q & 3];
                    e = e > 0.f ? e : 0.2f * e;
                    unsigned bit = (unsigned)(wv[fi][q & 3] >> (base + kk * 8 + (q >> 2))) & 1u;
                    float w = bit ? __expf(e) : 0.f;
                    zl += w;
                    pk.u[q] = f2bf(w);
                }
                if (fi) zs1 += zl; else zs0 += zl;
                af[fi][kk] = pk.v;
            }
        }
        // --- B loads + MFMA (B2 L2-resident; 4x256B dense per instr)
#pragma unroll
        for (int kk = 0; kk < 2; ++kk) {
            const ushort* bt = bb + (size_t)(jt * 8 + kk * 4) * 2048;
#pragma unroll
            for (int fj = 0; fj < 8; ++fj) {
                s16x8 bv = *reinterpret_cast<const s16x8*>(bt + fj * 128);
                acc[0][fj] = __builtin_amdgcn_mfma_f32_16x16x32_bf16(
                    af[0][kk], bv, acc[0][fj], 0, 0, 0);
                acc[1][fj] = __builtin_amdgcn_mfma_f32_16x16x32_bf16(
                    af[1][kk], bv, acc[1][fj], 0, 0, 0);
            }
        }
    }

    // --- combine phase 1: waves 0,1 write partials
    zs0 += __shfl_xor(zs0, 16); zs0 += __shfl_xor(zs0, 32);
    zs1 += __shfl_xor(zs1, 16); zs1 += __shfl_xor(zs1, 32);
    if (wid < 2) {
        float* myH = &Hlds[wid][0];
#pragma unroll
        for (int fi = 0; fi < 2; ++fi)
#pragma unroll
            for (int fj = 0; fj < 8; ++fj)
#pragma unroll
                for (int r = 0; r < 4; ++r)
                    myH[(fi * 16 + l4 * 4 + r) * HSTRIDE + fj * 16 + r15] = acc[fi][fj][r];
        if (lane < 16) {
            Zlds[wid][r15] = zs0;
            Zlds[wid][16 + r15] = zs1;
        }
    }
    __syncthreads();
    // --- combine phase 2: waves 2,3 add into regions 0,1
    if (wid >= 2) {
        float* myH = &Hlds[wid - 2][0];
#pragma unroll
        for (int fi = 0; fi < 2; ++fi)
#pragma unroll
            for (int fj = 0; fj < 8; ++fj)
#pragma unroll
                for (int r = 0; r < 4; ++r)
                    myH[(fi * 16 + l4 * 4 + r) * HSTRIDE + fj * 16 + r15] += acc[fi][fj][r];
        if (lane < 16) {
            Zlds[wid - 2][r15] += zs0;
            Zlds[wid - 2][16 + r15] += zs1;
        }
    }
    __syncthreads();

    // --- finalize: wave wid handles rows wid*8 .. wid*8+7
    const int c0 = 2 * lane;
    f32x2 fc1 = *reinterpret_cast<const f32x2*>(fcW + col0 + c0);
    f32x2 fc2 = *reinterpret_cast<const f32x2*>(fcW + NH + col0 + c0);
#pragma unroll
    for (int rr = 0; rr < 8; ++rr) {
        int row = wid * 8 + rr;
        float Z = Zlds[0][row] + Zlds[1][row];
        float inv = 1.f / Z;
        f32x2 h0 = *reinterpret_cast<const f32x2*>(&Hlds[0][row * HSTRIDE + c0]);
        f32x2 h1 = *reinterpret_cast<const f32x2*>(&Hlds[1][row * HSTRIDE + c0]);
        float ha = (h0[0] + h1[0]) * inv;
        float hb = (h0[1] + h1[1]) * inv;
        ha = ha > 0.f ? ha : expm1f(ha);   // elu
        hb = hb > 0.f ? hb : expm1f(hb);
        float d1 = ha * fc1[0] + hb * fc1[1];
        float d2 = ha * fc2[0] + hb * fc2[1];
        d1 = wave_red_add(d1);
        d2 = wave_red_add(d2);
        if (lane == 0) {
            out1h[cb * NN + row0 + row] = d1;
            ph[cb * NN + row0 + row] = d2;
        }
    }
}

// ---------------- K5: c = sum(ph) + fcb; out = out1h[0]+out1h[1] + c
__global__ __launch_bounds__(256) void k5_final(const float* __restrict__ out1h,
                                                const float* __restrict__ ph,
                                                const float* __restrict__ fcb,
                                                float* __restrict__ out) {
    __shared__ float red[256];
    int t = threadIdx.x;
    float s = 0.f;
    for (int i = t; i < 2 * NN; i += 256) s += ph[i];
    red[t] = s;
    __syncthreads();
    for (int h = 128; h; h >>= 1) {
        if (t < h) red[t] += red[t + h];
        __syncthreads();
    }
    float c = red[0] + fcb[0];
    for (int i = t; i < NN; i += 256) out[i] = out1h[i] + out1h[NN + i] + c;
}

extern "C" void kernel_launch(void* const* d_in, const int* in_sizes, int n_in,
                              void* d_out, int out_size, void* d_ws, size_t ws_size,
                              hipStream_t stream) {
    const float* x   = (const float*)d_in[0];
    const int*   adj = (const int*)d_in[1];
    const float* W   = (const float*)d_in[2];
    const float* a   = (const float*)d_in[3];
    const float* fcW = (const float*)d_in[4];
    const float* fcb = (const float*)d_in[5];
    float* out = (float*)d_out;
    char* ws = (char*)d_ws;

    // total = 14,893,056 B (well under proven 35.2 MB)
    constexpr size_t oWbT   = 0;                           // 256*512*2       = 262144
    constexpr size_t oB2    = oWbT + 262144;               // 768*256*8*2     = 3145728
    constexpr size_t oWh    = oB2 + 3145728;               // 6144*256*4      = 6291456
    constexpr size_t oF1    = oWh + 6291456;               // 24576
    constexpr size_t oF2    = oF1 + 24576;                 // 24576
    constexpr size_t oMask  = oF2 + 24576;                 // 6144*96*8       = 4718592
    constexpr size_t oOut1  = oMask + 4718592;             // 2*6144*4        = 49152
    constexpr size_t oP     = oOut1 + 49152;               // 2*6144*4        = 49152

    ushort* WbT  = (ushort*)(ws + oWbT);
    ushort* B2   = (ushort*)(ws + oB2);
    float*  Wh   = (float*)(ws + oWh);
    float*  f1   = (float*)(ws + oF1);
    float*  f2   = (float*)(ws + oF2);
    unsigned long long* mk = (unsigned long long*)(ws + oMask);
    float*  out1h = (float*)(ws + oOut1);
    float*  p    = (float*)(ws + oP);

    kprep<<<dim3(MASKBLK + 512), dim3(256), 0, stream>>>(adj, mk, W, WbT);
    k1_gemm<<<dim3(48, 4), dim3(256), 0, stream>>>(x, WbT, Wh, B2);
    k2_f12<<<dim3(1536), dim3(256), 0, stream>>>(Wh, a, f1, f2);
    k3_attn<<<dim3(192, 2), dim3(256), 0, stream>>>(mk, B2, f1, f2, fcW, out1h, p);
    k5_final<<<dim3(1), dim3(256), 0, stream>>>(out1h, p, fcb, out);
}

// Round 11
// 139.561 us; speedup vs baseline: 1.0462x; 1.0462x over previous
//
#include <hip/hip_runtime.h>
#include <hip/hip_bf16.h>

#define NN 6144
#define NF 512
#define NH 256
#define BR 32                  // K3 rows per block
#define NTT (NN / 64)          // 96 j-tiles total
#define NW (NN / 64)           // 96 mask words per row (24 groups x 4)
#define NG 24                  // mask groups (256 cols each)
#define HSTRIDE 132            // padded LDS row stride (f32)
#define MROWBLK 1536           // kmask: row blocks (4 rows each)

typedef __attribute__((ext_vector_type(4))) float f32x4;
typedef __attribute__((ext_vector_type(2))) float f32x2;
typedef __attribute__((ext_vector_type(8))) short s16x8;
typedef __attribute__((ext_vector_type(4))) short s16x4;
typedef __attribute__((ext_vector_type(4))) int i32x4;
typedef __attribute__((ext_vector_type(2))) unsigned long long u64x2;

__device__ __forceinline__ ushort f2bf(float f) {
    unsigned u = __builtin_bit_cast(unsigned, f);
    u += 0x7fffu + ((u >> 16) & 1u);   // RNE (finite values only)
    return (ushort)(u >> 16);
}

__device__ __forceinline__ float wave_red_add(float v) {
#pragma unroll
    for (int s = 32; s; s >>= 1) v += __shfl_xor(v, s);
    return v;
}

// ---------------- Kmask: adj -> interleaved u64 bitmask (+ W->WbT tail blocks)
// Wave = one row. Strict two-phase per batch: 8 int4 loads issued under full
// exec (8KB/wave in flight, sched_barrier-pinned), THEN ballots + one 4-lane
// u64 store per group. Format: word q of group g holds col g*256 + 4*lane + q
// at bit `lane` (same as R9/R10 — k3 unchanged).
__global__ __launch_bounds__(256) void kmask(const int* __restrict__ adj,
                                             unsigned long long* __restrict__ maskb,
                                             const float* __restrict__ W,
                                             ushort* __restrict__ WbT) {
    const int bid = blockIdx.x;
    const int t = threadIdx.x;
    if (bid >= MROWBLK) {
        int idx = (bid - MROWBLK) * 256 + t;   // 0..131071
        int k = idx >> 8, n = idx & 255;
        WbT[n * NF + k] = f2bf(W[idx]);
        return;
    }
    const int lane = t & 63, wid = t >> 6;
    const int row = bid * 4 + wid;
    const i32x4* ap = reinterpret_cast<const i32x4*>(adj + (size_t)row * NN) + lane;
    unsigned long long* mrow = maskb + (size_t)row * NW;
#pragma unroll
    for (int b = 0; b < 3; ++b) {
        // --- phase 1: issue all 8 loads (full exec, nothing between them)
        i32x4 v[8];
#pragma unroll
        for (int g = 0; g < 8; ++g)
            v[g] = ap[(b * 8 + g) * 64];
        __builtin_amdgcn_sched_barrier(0);
        // --- phase 2: ballots + single 4-lane store per group
#pragma unroll
        for (int g = 0; g < 8; ++g) {
            unsigned long long w0 = __ballot(v[g][0] != 0);
            unsigned long long w1 = __ballot(v[g][1] != 0);
            unsigned long long w2 = __ballot(v[g][2] != 0);
            unsigned long long w3 = __ballot(v[g][3] != 0);
            unsigned long long wsel = lane == 0 ? w0
                                    : lane == 1 ? w1
                                    : lane == 2 ? w2 : w3;
            if (lane < 4) mrow[(b * 8 + g) * 4 + lane] = wsel;
        }
    }
}

// ---------------- K1: Wh = x @ W  (6144x512 * 512x256), MFMA bf16
// outputs: Wh f32 [6144][256]; B2 bf16 blocked [j/8][col][j%8]
__global__ __launch_bounds__(256) void k1_gemm(const float* __restrict__ x,
                                               const ushort* __restrict__ WbT,
                                               float* __restrict__ Wh,
                                               ushort* __restrict__ B2) {
    __shared__ ushort Asm[128 * 64];   // [row][k] swizzled
    __shared__ ushort Bsm[64 * 64];    // [n][k] swizzled
    const int t = threadIdx.x, lane = t & 63, wid = t >> 6;
    const int rb = blockIdx.x;   // 0..47 (128 rows)
    const int cb = blockIdx.y;   // 0..3  (64 cols)
    const int wrow = wid >> 1, wcol = wid & 1;
    f32x4 acc[4][2];
#pragma unroll
    for (int i = 0; i < 4; ++i)
#pragma unroll
        for (int j = 0; j < 2; ++j) acc[i][j] = (f32x4){0.f, 0.f, 0.f, 0.f};

    for (int kt = 0; kt < NF; kt += 64) {
        __syncthreads();
#pragma unroll
        for (int c = 0; c < 4; ++c) {
            int idx = c * 256 + t;           // 0..1023
            int row = idx >> 3, k8 = idx & 7;
            const float* src = x + (rb * 128 + row) * NF + kt + k8 * 8;
            float4 lo = *reinterpret_cast<const float4*>(src);
            float4 hi = *reinterpret_cast<const float4*>(src + 4);
            union { s16x8 v; ushort u[8]; } pk;
            pk.u[0] = f2bf(lo.x); pk.u[1] = f2bf(lo.y);
            pk.u[2] = f2bf(lo.z); pk.u[3] = f2bf(lo.w);
            pk.u[4] = f2bf(hi.x); pk.u[5] = f2bf(hi.y);
            pk.u[6] = f2bf(hi.z); pk.u[7] = f2bf(hi.w);
            int byte = (row * 128 + k8 * 16) ^ ((row & 7) << 4);
            *reinterpret_cast<s16x8*>((char*)Asm + byte) = pk.v;
        }
#pragma unroll
        for (int c = 0; c < 2; ++c) {
            int idx = c * 256 + t;           // 0..511
            int row = idx >> 3, k8 = idx & 7;
            s16x8 v = *reinterpret_cast<const s16x8*>(WbT + (cb * 64 + row) * NF + kt + k8 * 8);
            int byte = (row * 128 + k8 * 16) ^ ((row & 7) << 4);
            *reinterpret_cast<s16x8*>((char*)Bsm + byte) = v;
        }
        __syncthreads();
#pragma unroll
        for (int kk = 0; kk < 64; kk += 32) {
            const int kbyte = (kk + ((lane >> 4) * 8)) * 2;
            s16x8 af[4], bfr[2];
#pragma unroll
            for (int fi = 0; fi < 4; ++fi) {
                int row = wrow * 64 + fi * 16 + (lane & 15);
                int byte = (row * 128 + kbyte) ^ ((row & 7) << 4);
                af[fi] = *reinterpret_cast<const s16x8*>((char*)Asm + byte);
            }
#pragma unroll
            for (int fj = 0; fj < 2; ++fj) {
                int nn = wcol * 32 + fj * 16 + (lane & 15);
                int byte = (nn * 128 + kbyte) ^ ((nn & 7) << 4);
                bfr[fj] = *reinterpret_cast<const s16x8*>((char*)Bsm + byte);
            }
#pragma unroll
            for (int fi = 0; fi < 4; ++fi)
#pragma unroll
                for (int fj = 0; fj < 2; ++fj)
                    acc[fi][fj] = __builtin_amdgcn_mfma_f32_16x16x32_bf16(
                        af[fi], bfr[fj], acc[fi][fj], 0, 0, 0);
        }
    }
#pragma unroll
    for (int fi = 0; fi < 4; ++fi)
#pragma unroll
        for (int fj = 0; fj < 2; ++fj) {
            int grow0 = rb * 128 + wrow * 64 + fi * 16 + (lane >> 4) * 4;  // j; %8 in {0,4}
            int gcol = cb * 64 + wcol * 32 + fj * 16 + (lane & 15);
            union { s16x4 v; ushort u[4]; } pk;
#pragma unroll
            for (int r = 0; r < 4; ++r) {
                float v = acc[fi][fj][r];
                Wh[(grow0 + r) * NH + gcol] = v;
                pk.u[r] = f2bf(v);
            }
            *reinterpret_cast<s16x4*>(B2 + (grow0 >> 3) * 2048 + gcol * 8 + (grow0 & 7)) = pk.v;
        }
}

// ---------------- K2: f1 = Wh@a1, f2 = Wh@a2 (one wave per row)
__global__ __launch_bounds__(256) void k2_f12(const float* __restrict__ Wh,
                                              const float* __restrict__ a,
                                              float* __restrict__ f1,
                                              float* __restrict__ f2) {
    int row = blockIdx.x * 4 + (threadIdx.x >> 6);
    int lane = threadIdx.x & 63;
    float4 wv = *reinterpret_cast<const float4*>(Wh + row * NH + lane * 4);
    float4 a1 = *reinterpret_cast<const float4*>(a + lane * 4);
    float4 a2 = *reinterpret_cast<const float4*>(a + NH + lane * 4);
    float d1 = wv.x * a1.x + wv.y * a1.y + wv.z * a1.z + wv.w * a1.w;
    float d2 = wv.x * a2.x + wv.y * a2.y + wv.z * a2.z + wv.w * a2.w;
    d1 = wave_red_add(d1);
    d2 = wave_red_add(d2);
    if (lane == 0) { f1[row] = d1; f2[row] = d2; }
}

// ---------------- K3: fully-fused attention — FINAL rows, no partial outputs
// Block: 32 rows x 128 cols (grid 192 x 2). 4 waves; wave wid sweeps tiles
// jt = wid + it*4 (jt&3 == wid), consuming the interleaved mask format:
// bit for col C+q = (word[q&3] >> (wid*16 + l4*2 + kk*8 + (q>>2))) & 1.
__global__ __launch_bounds__(256) void k3_attn(const unsigned long long* __restrict__ maskb,
                                               const ushort* __restrict__ B2,
                                               const float* __restrict__ f1,
                                               const float* __restrict__ f2,
                                               const float* __restrict__ fcW,
                                               float* __restrict__ out1h,
                                               float* __restrict__ ph) {
    __shared__ float Hlds[2][BR * HSTRIDE];   // 2 x 16.9 KB
    __shared__ float Zlds[2][BR];
    const int t = threadIdx.x, lane = t & 63, wid = t >> 6;
    const int rb = blockIdx.x;        // 0..191 (32 rows each)
    const int cb = blockIdx.y;        // 0..1   (128 cols each)
    const int row0 = rb * BR;
    const int col0 = cb * 128;
    const int r15 = lane & 15, l4 = lane >> 4;
    const int sh = l4 * 8;
    const int base = wid * 16 + l4 * 2;   // bit base within mask words

    const float f1v0 = f1[row0 + r15];
    const float f1v1 = f1[row0 + 16 + r15];
    const unsigned long long* mp0 = maskb + (size_t)(row0 + r15) * NW;
    const unsigned long long* mp1 = mp0 + 16 * NW;
    const float* f2p = f2 + sh;
    const ushort* bb = B2 + (size_t)l4 * 2048 + (col0 + r15) * 8;

    f32x4 acc[2][8];
#pragma unroll
    for (int i = 0; i < 2; ++i)
#pragma unroll
        for (int j = 0; j < 8; ++j) acc[i][j] = (f32x4){0.f, 0.f, 0.f, 0.f};
    float zs0 = 0.f, zs1 = 0.f;

#pragma unroll 2
    for (int it = 0; it < NG; ++it) {
        const int jt = wid + it * 4;
        // group mask words (interleaved format), both row-halves
        u64x2 wAa = *reinterpret_cast<const u64x2*>(mp0 + it * 4);
        u64x2 wAb = *reinterpret_cast<const u64x2*>(mp0 + it * 4 + 2);
        u64x2 wBa = *reinterpret_cast<const u64x2*>(mp1 + it * 4);
        u64x2 wBb = *reinterpret_cast<const u64x2*>(mp1 + it * 4 + 2);
        unsigned long long wv[2][4] = {{wAa[0], wAa[1], wAb[0], wAb[1]},
                                       {wBa[0], wBa[1], wBb[0], wBb[1]}};
        f32x4 g[2][2];
#pragma unroll
        for (int kk = 0; kk < 2; ++kk)
#pragma unroll
            for (int h = 0; h < 2; ++h)
                g[kk][h] = *reinterpret_cast<const f32x4*>(f2p + jt * 64 + kk * 32 + h * 4);
        // --- wgen: build A-fragments in registers from interleaved mask bits
        s16x8 af[2][2];
#pragma unroll
        for (int fi = 0; fi < 2; ++fi) {
            const float f1v = fi ? f1v1 : f1v0;
#pragma unroll
            for (int kk = 0; kk < 2; ++kk) {
                union { s16x8 v; ushort u[8]; } pk;
                float zl = 0.f;
#pragma unroll
                for (int q = 0; q < 8; ++q) {
                    float e = f1v + g[kk][q >> 2][q & 3];
                    e = e > 0.f ? e : 0.2f * e;
                    unsigned bit = (unsigned)(wv[fi][q & 3] >> (base + kk * 8 + (q >> 2))) & 1u;
                    float w = bit ? __expf(e) : 0.f;
                    zl += w;
                    pk.u[q] = f2bf(w);
                }
                if (fi) zs1 += zl; else zs0 += zl;
                af[fi][kk] = pk.v;
            }
        }
        // --- B loads + MFMA (B2 L2-resident; 4x256B dense per instr)
#pragma unroll
        for (int kk = 0; kk < 2; ++kk) {
            const ushort* bt = bb + (size_t)(jt * 8 + kk * 4) * 2048;
#pragma unroll
            for (int fj = 0; fj < 8; ++fj) {
                s16x8 bv = *reinterpret_cast<const s16x8*>(bt + fj * 128);
                acc[0][fj] = __builtin_amdgcn_mfma_f32_16x16x32_bf16(
                    af[0][kk], bv, acc[0][fj], 0, 0, 0);
                acc[1][fj] = __builtin_amdgcn_mfma_f32_16x16x32_bf16(
                    af[1][kk], bv, acc[1][fj], 0, 0, 0);
            }
        }
    }

    // --- combine phase 1: waves 0,1 write partials
    zs0 += __shfl_xor(zs0, 16); zs0 += __shfl_xor(zs0, 32);
    zs1 += __shfl_xor(zs1, 16); zs1 += __shfl_xor(zs1, 32);
    if (wid < 2) {
        float* myH = &Hlds[wid][0];
#pragma unroll
        for (int fi = 0; fi < 2; ++fi)
#pragma unroll
            for (int fj = 0; fj < 8; ++fj)
#pragma unroll
                for (int r = 0; r < 4; ++r)
                    myH[(fi * 16 + l4 * 4 + r) * HSTRIDE + fj * 16 + r15] = acc[fi][fj][r];
        if (lane < 16) {
            Zlds[wid][r15] = zs0;
            Zlds[wid][16 + r15] = zs1;
        }
    }
    __syncthreads();
    // --- combine phase 2: waves 2,3 add into regions 0,1
    if (wid >= 2) {
        float* myH = &Hlds[wid - 2][0];
#pragma unroll
        for (int fi = 0; fi < 2; ++fi)
#pragma unroll
            for (int fj = 0; fj < 8; ++fj)
#pragma unroll
                for (int r = 0; r < 4; ++r)
                    myH[(fi * 16 + l4 * 4 + r) * HSTRIDE + fj * 16 + r15] += acc[fi][fj][r];
        if (lane < 16) {
            Zlds[wid - 2][r15] += zs0;
            Zlds[wid - 2][16 + r15] += zs1;
        }
    }
    __syncthreads();

    // --- finalize: wave wid handles rows wid*8 .. wid*8+7
    const int c0 = 2 * lane;
    f32x2 fc1 = *reinterpret_cast<const f32x2*>(fcW + col0 + c0);
    f32x2 fc2 = *reinterpret_cast<const f32x2*>(fcW + NH + col0 + c0);
#pragma unroll
    for (int rr = 0; rr < 8; ++rr) {
        int row = wid * 8 + rr;
        float Z = Zlds[0][row] + Zlds[1][row];
        float inv = 1.f / Z;
        f32x2 h0 = *reinterpret_cast<const f32x2*>(&Hlds[0][row * HSTRIDE + c0]);
        f32x2 h1 = *reinterpret_cast<const f32x2*>(&Hlds[1][row * HSTRIDE + c0]);
        float ha = (h0[0] + h1[0]) * inv;
        float hb = (h0[1] + h1[1]) * inv;
        ha = ha > 0.f ? ha : expm1f(ha);   // elu
        hb = hb > 0.f ? hb : expm1f(hb);
        float d1 = ha * fc1[0] + hb * fc1[1];
        float d2 = ha * fc2[0] + hb * fc2[1];
        d1 = wave_red_add(d1);
        d2 = wave_red_add(d2);
        if (lane == 0) {
            out1h[cb * NN + row0 + row] = d1;
            ph[cb * NN + row0 + row] = d2;
        }
    }
}

// ---------------- K5: c = sum(ph) + fcb; out = out1h[0]+out1h[1] + c
__global__ __launch_bounds__(256) void k5_final(const float* __restrict__ out1h,
                                                const float* __restrict__ ph,
                                                const float* __restrict__ fcb,
                                                float* __restrict__ out) {
    __shared__ float red[256];
    int t = threadIdx.x;
    float s = 0.f;
    for (int i = t; i < 2 * NN; i += 256) s += ph[i];
    red[t] = s;
    __syncthreads();
    for (int h = 128; h; h >>= 1) {
        if (t < h) red[t] += red[t + h];
        __syncthreads();
    }
    float c = red[0] + fcb[0];
    for (int i = t; i < NN; i += 256) out[i] = out1h[i] + out1h[NN + i] + c;
}

extern "C" void kernel_launch(void* const* d_in, const int* in_sizes, int n_in,
                              void* d_out, int out_size, void* d_ws, size_t ws_size,
                              hipStream_t stream) {
    const float* x   = (const float*)d_in[0];
    const int*   adj = (const int*)d_in[1];
    const float* W   = (const float*)d_in[2];
    const float* a   = (const float*)d_in[3];
    const float* fcW = (const float*)d_in[4];
    const float* fcb = (const float*)d_in[5];
    float* out = (float*)d_out;
    char* ws = (char*)d_ws;

    // total = 14,893,056 B (well under proven 35.2 MB)
    constexpr size_t oWbT   = 0;                           // 256*512*2       = 262144
    constexpr size_t oB2    = oWbT + 262144;               // 768*256*8*2     = 3145728
    constexpr size_t oWh    = oB2 + 3145728;               // 6144*256*4      = 6291456
    constexpr size_t oF1    = oWh + 6291456;               // 24576
    constexpr size_t oF2    = oF1 + 24576;                 // 24576
    constexpr size_t oMask  = oF2 + 24576;                 // 6144*96*8       = 4718592
    constexpr size_t oOut1  = oMask + 4718592;             // 2*6144*4        = 49152
    constexpr size_t oP     = oOut1 + 49152;               // 2*6144*4        = 49152

    ushort* WbT  = (ushort*)(ws + oWbT);
    ushort* B2   = (ushort*)(ws + oB2);
    float*  Wh   = (float*)(ws + oWh);
    float*  f1   = (float*)(ws + oF1);
    float*  f2   = (float*)(ws + oF2);
    unsigned long long* mk = (unsigned long long*)(ws + oMask);
    float*  out1h = (float*)(ws + oOut1);
    float*  p    = (float*)(ws + oP);

    kmask<<<dim3(MROWBLK + 512), dim3(256), 0, stream>>>(adj, mk, W, WbT);
    k1_gemm<<<dim3(48, 4), dim3(256), 0, stream>>>(x, WbT, Wh, B2);
    k2_f12<<<dim3(1536), dim3(256), 0, stream>>>(Wh, a, f1, f2);
    k3_attn<<<dim3(192, 2), dim3(256), 0, stream>>>(mk, B2, f1, f2, fcW, out1h, p);
    k5_final<<<dim3(1), dim3(256), 0, stream>>>(out1h, p, fcb, out);
}